// Round 3
// baseline (420.017 us; speedup 1.0000x reference)
//
#include <hip/hip_runtime.h>
#include <hip/hip_bf16.h>
#include <hip/hip_cooperative_groups.h>

namespace cg = cooperative_groups;

#define I_DIM  512
#define O_DIM  512
#define NBATCH 1024
#define NSPL   8            // spline coeffs per input channel
#define KPI    12           // K slots per input channel: 8 spline + s_hi,s_hi,s_lo,0
#define KDIM   (I_DIM * KPI)   // 6144
#define NGRID  12           // extended grid points per channel
#define SPLITK 8
#define KSEG   (KDIM / SPLITK) // 768
#define BK     64              // bf16 elems per LDS row; 128 B

// fused kernel geometry: 256 blocks x 512 threads = 1 block/CU (co-residency safe)
#define NBLK 256
#define TPB  512
#define NTH  (NBLK * TPB)      // 131072 threads

typedef __attribute__((ext_vector_type(8))) short bf16x8;
typedef __attribute__((ext_vector_type(4))) float f32x4;

// ---------------------------------------------------------------------------
// async global->LDS 16B: dest = wave-uniform base + lane*16 (m97/m104 semantics)
// ---------------------------------------------------------------------------
__device__ __forceinline__ void gload_lds16(const __hip_bfloat16* g, __hip_bfloat16* l) {
    __builtin_amdgcn_global_load_lds(
        (const __attribute__((address_space(1))) void*)g,
        (__attribute__((address_space(3))) void*)l, 16, 0, 0);
}

// ---------------------------------------------------------------------------
// Feature row: F[b][i*12+slot] = [B0..B7, s_hi, s_hi, s_lo, 0] (bf16).
// Paired with Wt slots [spline*8, w_hi, w_lo, w_hi, 0]:
//   s_hi*w_hi + s_hi*w_lo + s_lo*w_hi ~= silu(x)*sb  (rel err ~2^-17)
// ---------------------------------------------------------------------------
__device__ __forceinline__ void features_core(float xv, const float* __restrict__ grid,
                                              int i, __hip_bfloat16* __restrict__ dst) {
    float g[NGRID];
#pragma unroll
    for (int j = 0; j < NGRID; ++j) g[j] = grid[i * NGRID + j];

    float B[NGRID - 1];
#pragma unroll
    for (int j = 0; j < NGRID - 1; ++j)
        B[j] = (xv >= g[j] && xv < g[j + 1]) ? 1.0f : 0.0f;
#pragma unroll
    for (int p = 1; p <= 3; ++p) {
#pragma unroll
        for (int j = 0; j < NGRID - 1 - p; ++j) {
            B[j] = (xv - g[j]) / (g[j + p] - g[j]) * B[j]
                 + (g[j + p + 1] - xv) / (g[j + p + 1] - g[j + 1]) * B[j + 1];
        }
    }
    float s = xv / (1.0f + __expf(-xv));  // silu
    __hip_bfloat16 shi = __float2bfloat16(s);
    __hip_bfloat16 slo = __float2bfloat16(s - __bfloat162float(shi));

    __align__(16) __hip_bfloat16 row[KPI];
#pragma unroll
    for (int k = 0; k < NSPL; ++k) row[k] = __float2bfloat16(B[k]);
    row[8]  = shi;
    row[9]  = shi;
    row[10] = slo;
    row[11] = __float2bfloat16(0.0f);

    uint2* d = (uint2*)dst;
    const uint2* srow = (const uint2*)row;
    d[0] = srow[0]; d[1] = srow[1]; d[2] = srow[2];
}

__device__ __forceinline__ void wt_row_core(const float* __restrict__ coef,
                                            const float* __restrict__ sb,
                                            const float* __restrict__ sp,
                                            int i, int o,
                                            __hip_bfloat16* __restrict__ W) {
    float sbv = sb[i * O_DIM + o];
    float spv = sp[i * O_DIM + o];
    const float* cf = coef + (size_t)(i * O_DIM + o) * NSPL;
    __align__(16) __hip_bfloat16 row[KPI];
#pragma unroll
    for (int k = 0; k < NSPL; ++k) row[k] = __float2bfloat16(spv * cf[k]);
    __hip_bfloat16 whi = __float2bfloat16(sbv);
    __hip_bfloat16 wlo = __float2bfloat16(sbv - __bfloat162float(whi));
    row[8]  = whi;
    row[9]  = wlo;
    row[10] = whi;
    row[11] = __float2bfloat16(0.0f);
    uint2* dst = (uint2*)(W + (size_t)o * KDIM + i * KPI);
    const uint2* src = (const uint2*)row;
    dst[0] = src[0]; dst[1] = src[1]; dst[2] = src[2];
}

// ---------------------------------------------------------------------------
// Fused-path GEMM tile: BM=128 x BN=128, 8 waves (2 along M x 4 along N),
// each wave 64x32 (acc[4][2]) — same inner loop & FLOP/LDS-byte as R1.
// XOR-swizzled LDS (chunk j of row r at j^(r&7); 2-way aliasing free, m136).
// bid -> (bm 0..7, bn 0..3, ks 0..7): 256 tiles == 256 blocks.
// ---------------------------------------------------------------------------
__device__ __forceinline__ void gemm_tile8(const __hip_bfloat16* __restrict__ A,
                                           const __hip_bfloat16* __restrict__ W,
                                           float* __restrict__ P,
                                           __hip_bfloat16* lA, __hip_bfloat16* lB,
                                           int bid, int tid) {
    int bm = bid >> 5;          // 0..7
    int bn = (bid >> 3) & 3;    // 0..3
    int ks = bid & 7;           // 0..7
    int lane = tid & 63;
    int wave = tid >> 6;        // 0..7
    int wr = (wave & 1) * 64;   // wave m-offset (2 waves along M)
    int wc = (wave >> 1) * 32;  // wave n-offset (4 waves along N)
    int q  = lane >> 4;         // 0..3
    int ln = lane & 15;

    f32x4 acc[4][2];
#pragma unroll
    for (int a = 0; a < 4; ++a)
#pragma unroll
        for (int b = 0; b < 2; ++b) acc[a][b] = (f32x4){0.f, 0.f, 0.f, 0.f};

    const __hip_bfloat16* Abase = A + (size_t)(bm * 128) * KDIM + ks * KSEG;
    const __hip_bfloat16* Bbase = W + (size_t)(bn * 128) * KDIM + ks * KSEG;

    for (int kt = 0; kt < KSEG; kt += BK) {
        __syncthreads();
        // A: 1024 chunks of 16B (128 rows x 8); 8 waves cover it in 2 calls each.
        // LDS dest wave-uniform base (HW adds lane*16); source chunk
        // j = (pos&7) ^ (row&7) (XOR swizzle).
#pragma unroll
        for (int c = 0; c < 2; ++c) {
            int cc = wave * 128 + c * 64 + lane;
            int r = cc >> 3, j = (cc & 7) ^ (r & 7);
            gload_lds16(Abase + (size_t)r * KDIM + kt + j * 8,
                        lA + (size_t)(wave * 128 + c * 64) * 8);
        }
        // B: 1024 chunks (128 rows x 8), same pattern.
#pragma unroll
        for (int c = 0; c < 2; ++c) {
            int cc = wave * 128 + c * 64 + lane;
            int r = cc >> 3, j = (cc & 7) ^ (r & 7);
            gload_lds16(Bbase + (size_t)r * KDIM + kt + j * 8,
                        lB + (size_t)(wave * 128 + c * 64) * 8);
        }
        __syncthreads();   // vmcnt(0) drain before s_barrier

#pragma unroll
        for (int kh = 0; kh < 2; ++kh) {
            bf16x8 af[4], bfr[2];
#pragma unroll
            for (int rt = 0; rt < 4; ++rt) {
                int row = wr + rt * 16 + ln;
                af[rt] = *(const bf16x8*)(lA + row * BK + (((kh * 4 + q) ^ (row & 7)) * 8));
            }
#pragma unroll
            for (int ct = 0; ct < 2; ++ct) {
                int row = wc + ct * 16 + ln;
                bfr[ct] = *(const bf16x8*)(lB + row * BK + (((kh * 4 + q) ^ (row & 7)) * 8));
            }
#pragma unroll
            for (int rt = 0; rt < 4; ++rt)
#pragma unroll
                for (int ct = 0; ct < 2; ++ct)
                    acc[rt][ct] = __builtin_amdgcn_mfma_f32_16x16x32_bf16(
                        af[rt], bfr[ct], acc[rt][ct], 0, 0, 0);
        }
    }

    // epilogue: C/D layout col = lane&15, row = quad*4 + reg
    float* Pp = P + (size_t)ks * NBATCH * O_DIM;
    int orow = bm * 128 + wr;
    int ocol = bn * 128 + wc + ln;
#pragma unroll
    for (int rt = 0; rt < 4; ++rt)
#pragma unroll
        for (int ct = 0; ct < 2; ++ct)
#pragma unroll
            for (int r = 0; r < 4; ++r)
                Pp[(size_t)(orow + rt * 16 + q * 4 + r) * O_DIM + ocol + ct * 16]
                    = acc[rt][ct][r];
}

// ---------------------------------------------------------------------------
// R3: persistent cooperative kernel, grid sized for UNCONDITIONAL co-residency
// (256 blocks = 1/CU; R2's 512 = exact theoretical max likely failed launch
// validation -> zeros -> absmax 0.154 ~ max|ref|). 512 thr/block keeps
// 8 waves/CU in the GEMM phases via a 128x128 tile (same 64x32 wave tile).
// Host falls back to the verified R1 multi-kernel path if the cooperative
// launch is rejected.
// ---------------------------------------------------------------------------
__global__ __launch_bounds__(TPB, 2)
void kan_fused(const float* __restrict__ x0,
               const float* __restrict__ gr0, const float* __restrict__ gr1,
               const float* __restrict__ gr2,
               const float* __restrict__ c0, const float* __restrict__ sb0, const float* __restrict__ sp0,
               const float* __restrict__ c1, const float* __restrict__ sb1, const float* __restrict__ sp1,
               const float* __restrict__ c2, const float* __restrict__ sb2, const float* __restrict__ sp2,
               __hip_bfloat16* __restrict__ Wt,   // [3][O_DIM][KDIM]
               __hip_bfloat16* __restrict__ F,    // [NBATCH][KDIM]
               float* __restrict__ P,             // [SPLITK][NBATCH][O_DIM]
               float* __restrict__ out) {         // [NBATCH][O_DIM]
    __shared__ __hip_bfloat16 lA[128 * BK];   // 16 KB
    __shared__ __hip_bfloat16 lB[128 * BK];   // 16 KB

    cg::grid_group gg = cg::this_grid();
    const int tid  = threadIdx.x;
    const int bid  = blockIdx.x;
    const int gtid = bid * TPB + tid;

    // ---- phase 0a: build Wt, all 3 layers (786432 rows / 131072 thr = 6) ----
#pragma unroll
    for (int it = 0; it < 6; ++it) {
        int e = gtid + it * NTH;
        int l = e >> 18;                       // uniform per iteration
        const float* coef = l == 0 ? c0  : (l == 1 ? c1  : c2);
        const float* sb   = l == 0 ? sb0 : (l == 1 ? sb1 : sb2);
        const float* sp   = l == 0 ? sp0 : (l == 1 ? sp1 : sp2);
        int rem = e & (I_DIM * O_DIM - 1);
        wt_row_core(coef, sb, sp, rem & (I_DIM - 1), rem >> 9,
                    Wt + (size_t)l * O_DIM * KDIM);
    }

    // ---- phase 0b: features from x (524288 / 131072 = 4) ----
#pragma unroll
    for (int it = 0; it < 4; ++it) {
        int e = gtid + it * NTH;
        features_core(x0[e], gr0, e & (I_DIM - 1), F + (size_t)e * KPI);
    }
    gg.sync();

    // ---- layer 0 GEMM ----
    gemm_tile8(F, Wt, P, lA, lB, bid, tid);
    gg.sync();

    // ---- featsum -> features (layer 1 input) ----
#pragma unroll
    for (int it = 0; it < 4; ++it) {
        int e = gtid + it * NTH;
        float xv = 0.f;
#pragma unroll
        for (int s = 0; s < SPLITK; ++s) xv += P[(size_t)s * NBATCH * I_DIM + e];
        features_core(xv, gr1, e & (I_DIM - 1), F + (size_t)e * KPI);
    }
    gg.sync();

    // ---- layer 1 GEMM ----
    gemm_tile8(F, Wt + (size_t)O_DIM * KDIM, P, lA, lB, bid, tid);
    gg.sync();

    // ---- featsum -> features (layer 2 input) ----
#pragma unroll
    for (int it = 0; it < 4; ++it) {
        int e = gtid + it * NTH;
        float xv = 0.f;
#pragma unroll
        for (int s = 0; s < SPLITK; ++s) xv += P[(size_t)s * NBATCH * I_DIM + e];
        features_core(xv, gr2, e & (I_DIM - 1), F + (size_t)e * KPI);
    }
    gg.sync();

    // ---- layer 2 GEMM ----
    gemm_tile8(F, Wt + (size_t)2 * O_DIM * KDIM, P, lA, lB, bid, tid);
    gg.sync();

    // ---- reduce splitK partials -> out ----
#pragma unroll
    for (int it = 0; it < 4; ++it) {
        int e = gtid + it * NTH;
        float v = 0.f;
#pragma unroll
        for (int s = 0; s < SPLITK; ++s) v += P[(size_t)s * NBATCH * O_DIM + e];
        out[e] = v;
    }
}

// ===========================================================================
// Fallback path: verified R1 multi-kernel pipeline (used only if the
// cooperative launch is rejected by the runtime).
// ===========================================================================
__global__ void build_wt_all(const float* __restrict__ c0, const float* __restrict__ b0, const float* __restrict__ p0,
                             const float* __restrict__ c1, const float* __restrict__ b1, const float* __restrict__ p1,
                             const float* __restrict__ c2, const float* __restrict__ b2, const float* __restrict__ p2,
                             __hip_bfloat16* __restrict__ Wt) {
    int l = blockIdx.y;
    const float* coef = l == 0 ? c0 : (l == 1 ? c1 : c2);
    const float* sb   = l == 0 ? b0 : (l == 1 ? b1 : b2);
    const float* sp   = l == 0 ? p0 : (l == 1 ? p1 : p2);
    int tid = blockIdx.x * blockDim.x + threadIdx.x;  // o*512 + i
    wt_row_core(coef, sb, sp, tid & (I_DIM - 1), tid >> 9,
                Wt + (size_t)l * O_DIM * KDIM);
}

__global__ void build_features_x(const float* __restrict__ x,
                                 const float* __restrict__ grid,
                                 __hip_bfloat16* __restrict__ F) {
    int tid = blockIdx.x * blockDim.x + threadIdx.x;  // b*512+i
    features_core(x[tid], grid, tid & (I_DIM - 1), F + (size_t)tid * KPI);
}

__global__ void build_features_sum(const float* __restrict__ P,
                                   const float* __restrict__ grid,
                                   __hip_bfloat16* __restrict__ F) {
    int tid = blockIdx.x * blockDim.x + threadIdx.x;
    float xv = 0.f;
#pragma unroll
    for (int s = 0; s < SPLITK; ++s) xv += P[(size_t)s * NBATCH * I_DIM + tid];
    features_core(xv, grid, tid & (I_DIM - 1), F + (size_t)tid * KPI);
}

__global__ void reduce_out(const float* __restrict__ P, float* __restrict__ out) {
    int tid = blockIdx.x * blockDim.x + threadIdx.x;
    float v = 0.f;
#pragma unroll
    for (int s = 0; s < SPLITK; ++s) v += P[(size_t)s * NBATCH * O_DIM + tid];
    out[tid] = v;
}

// R1 GEMM: BM=128 x BN=64, 4 waves, wave tile 64x32.
__global__ __launch_bounds__(256)
void gemm_kernel_fb(const __hip_bfloat16* __restrict__ A,
                    const __hip_bfloat16* __restrict__ Wt,
                    float* __restrict__ P) {
    __shared__ __hip_bfloat16 lA[128 * BK];  // 16 KB
    __shared__ __hip_bfloat16 lB[64 * BK];   // 8 KB

    int bm = blockIdx.x;        // 0..7
    int bn = blockIdx.y;        // 0..7
    int ks = blockIdx.z;        // 0..7
    int tid = threadIdx.x;
    int lane = tid & 63;
    int wave = tid >> 6;
    int wr = (wave & 1) * 64;
    int wc = (wave >> 1) * 32;
    int q  = lane >> 4;
    int ln = lane & 15;

    f32x4 acc[4][2];
#pragma unroll
    for (int a = 0; a < 4; ++a)
#pragma unroll
        for (int b = 0; b < 2; ++b) acc[a][b] = (f32x4){0.f, 0.f, 0.f, 0.f};

    const __hip_bfloat16* Abase = A  + (size_t)(bm * 128) * KDIM + ks * KSEG;
    const __hip_bfloat16* Bbase = Wt + (size_t)(bn * 64) * KDIM + ks * KSEG;

    for (int kt = 0; kt < KSEG; kt += BK) {
        __syncthreads();
#pragma unroll
        for (int c = 0; c < 4; ++c) {
            int cc = wave * 256 + c * 64 + lane;
            int r = cc >> 3, j = (cc & 7) ^ (r & 7);
            gload_lds16(Abase + (size_t)r * KDIM + kt + j * 8,
                        lA + (size_t)(wave * 256 + c * 64) * 8);
        }
#pragma unroll
        for (int c = 0; c < 2; ++c) {
            int cc = wave * 128 + c * 64 + lane;
            int r = cc >> 3, j = (cc & 7) ^ (r & 7);
            gload_lds16(Bbase + (size_t)r * KDIM + kt + j * 8,
                        lB + (size_t)(wave * 128 + c * 64) * 8);
        }
        __syncthreads();

#pragma unroll
        for (int kh = 0; kh < 2; ++kh) {
            bf16x8 af[4], bfr[2];
#pragma unroll
            for (int rt = 0; rt < 4; ++rt) {
                int row = wr + rt * 16 + ln;
                af[rt] = *(const bf16x8*)(lA + row * BK + (((kh * 4 + q) ^ (row & 7)) * 8));
            }
#pragma unroll
            for (int ct = 0; ct < 2; ++ct) {
                int row = wc + ct * 16 + ln;
                bfr[ct] = *(const bf16x8*)(lB + row * BK + (((kh * 4 + q) ^ (row & 7)) * 8));
            }
#pragma unroll
            for (int rt = 0; rt < 4; ++rt)
#pragma unroll
                for (int ct = 0; ct < 2; ++ct)
                    acc[rt][ct] = __builtin_amdgcn_mfma_f32_16x16x32_bf16(
                        af[rt], bfr[ct], acc[rt][ct], 0, 0, 0);
        }
    }

    float* Pp = P + (size_t)ks * NBATCH * O_DIM;
    int orow = bm * 128 + wr;
    int ocol = bn * 64 + wc + ln;
#pragma unroll
    for (int rt = 0; rt < 4; ++rt)
#pragma unroll
        for (int ct = 0; ct < 2; ++ct)
#pragma unroll
            for (int r = 0; r < 4; ++r)
                Pp[(size_t)(orow + rt * 16 + q * 4 + r) * O_DIM + ocol + ct * 16]
                    = acc[rt][ct][r];
}

// ---------------------------------------------------------------------------
extern "C" void kernel_launch(void* const* d_in, const int* in_sizes, int n_in,
                              void* d_out, int out_size, void* d_ws, size_t ws_size,
                              hipStream_t stream) {
    const float* x0  = (const float*)d_in[0];
    const float* gr0 = (const float*)d_in[1];
    const float* c0  = (const float*)d_in[2];
    const float* sb0 = (const float*)d_in[3];
    const float* sp0 = (const float*)d_in[4];
    const float* gr1 = (const float*)d_in[5];
    const float* c1  = (const float*)d_in[6];
    const float* sb1 = (const float*)d_in[7];
    const float* sp1 = (const float*)d_in[8];
    const float* gr2 = (const float*)d_in[9];
    const float* c2  = (const float*)d_in[10];
    const float* sb2 = (const float*)d_in[11];
    const float* sp2 = (const float*)d_in[12];

    char* ws = (char*)d_ws;
    const size_t wt_bytes = (size_t)O_DIM * KDIM * sizeof(__hip_bfloat16);   // 6.3 MB/layer
    const size_t f_bytes  = (size_t)NBATCH * KDIM * sizeof(__hip_bfloat16);  // 12.6 MB
    __hip_bfloat16* Wt = (__hip_bfloat16*)ws;                  // 3 layers contiguous
    __hip_bfloat16* F  = (__hip_bfloat16*)(ws + 3 * wt_bytes);
    float* P = (float*)(ws + 3 * wt_bytes + f_bytes);          // [8][1024][512] = 16.8 MB
    float* out = (float*)d_out;

    void* args[] = {&x0, &gr0, &gr1, &gr2,
                    &c0, &sb0, &sp0, &c1, &sb1, &sp1, &c2, &sb2, &sp2,
                    &Wt, &F, &P, &out};

    hipError_t err = hipLaunchCooperativeKernel(
        reinterpret_cast<const void*>(kan_fused),
        dim3(NBLK), dim3(TPB), args, 0, stream);

    if (err != hipSuccess) {
        (void)hipGetLastError();   // clear sticky error; run verified R1 path
        build_wt_all<<<dim3((I_DIM * O_DIM) / 256, 3), 256, 0, stream>>>(
            c0, sb0, sp0, c1, sb1, sp1, c2, sb2, sp2, Wt);
        build_features_x<<<(NBATCH * I_DIM) / 256, 256, 0, stream>>>(x0, gr0, F);
        gemm_kernel_fb<<<dim3(8, 8, SPLITK), 256, 0, stream>>>(F, Wt, P);
        build_features_sum<<<(NBATCH * I_DIM) / 256, 256, 0, stream>>>(P, gr1, F);
        gemm_kernel_fb<<<dim3(8, 8, SPLITK), 256, 0, stream>>>(F, Wt + (size_t)O_DIM * KDIM, P);
        build_features_sum<<<(NBATCH * I_DIM) / 256, 256, 0, stream>>>(P, gr2, F);
        gemm_kernel_fb<<<dim3(8, 8, SPLITK), 256, 0, stream>>>(F, Wt + (size_t)2 * O_DIM * KDIM, P);
        reduce_out<<<(NBATCH * O_DIM) / 256, 256, 0, stream>>>(P, out);
    }
}

// Round 4
// 199.897 us; speedup vs baseline: 2.1012x; 2.1012x over previous
//
#include <hip/hip_runtime.h>
#include <hip/hip_bf16.h>

#define I_DIM  512
#define O_DIM  512
#define NBATCH 1024
#define NSPL   8            // spline coeffs per input channel
#define KPI    12           // K slots per input channel: 8 spline + s_hi,s_hi,s_lo,0
#define KDIM   (I_DIM * KPI)   // 6144
#define NGRID  12           // extended grid points per channel

#define SPLITK 4
#define KSEG   (KDIM / SPLITK) // 1536
#define BK     64              // bf16 elems per LDS row; 128 B
#define BM     64
#define BN     64

typedef __attribute__((ext_vector_type(8))) short bf16x8;
typedef __attribute__((ext_vector_type(4))) float f32x4;

// ---------------------------------------------------------------------------
// async global->LDS 16B: dest = wave-uniform base + lane*16 (m97/m104 semantics)
// ---------------------------------------------------------------------------
__device__ __forceinline__ void gload_lds16(const __hip_bfloat16* g, __hip_bfloat16* l) {
    __builtin_amdgcn_global_load_lds(
        (const __attribute__((address_space(1))) void*)g,
        (__attribute__((address_space(3))) void*)l, 16, 0, 0);
}

// ---------------------------------------------------------------------------
// Feature row: F[b][i*12+slot] = [B0..B7, s_hi, s_hi, s_lo, 0] (bf16).
// Paired with Wt slots [spline*8, w_hi, w_lo, w_hi, 0]:
//   s_hi*w_hi + s_hi*w_lo + s_lo*w_hi ~= silu(x)*sb  (rel err ~2^-17)
// ---------------------------------------------------------------------------
__device__ __forceinline__ void features_core(float xv, const float* __restrict__ grid,
                                              int i, __hip_bfloat16* __restrict__ dst) {
    float g[NGRID];
#pragma unroll
    for (int j = 0; j < NGRID; ++j) g[j] = grid[i * NGRID + j];

    float B[NGRID - 1];
#pragma unroll
    for (int j = 0; j < NGRID - 1; ++j)
        B[j] = (xv >= g[j] && xv < g[j + 1]) ? 1.0f : 0.0f;
#pragma unroll
    for (int p = 1; p <= 3; ++p) {
#pragma unroll
        for (int j = 0; j < NGRID - 1 - p; ++j) {
            B[j] = (xv - g[j]) / (g[j + p] - g[j]) * B[j]
                 + (g[j + p + 1] - xv) / (g[j + p + 1] - g[j + 1]) * B[j + 1];
        }
    }
    float s = xv / (1.0f + __expf(-xv));  // silu
    __hip_bfloat16 shi = __float2bfloat16(s);
    __hip_bfloat16 slo = __float2bfloat16(s - __bfloat162float(shi));

    __align__(16) __hip_bfloat16 row[KPI];
#pragma unroll
    for (int k = 0; k < NSPL; ++k) row[k] = __float2bfloat16(B[k]);
    row[8]  = shi;
    row[9]  = shi;
    row[10] = slo;
    row[11] = __float2bfloat16(0.0f);

    uint2* d = (uint2*)dst;
    const uint2* srow = (const uint2*)row;
    d[0] = srow[0]; d[1] = srow[1]; d[2] = srow[2];
}

__device__ __forceinline__ void wt_row_core(const float* __restrict__ coef,
                                            const float* __restrict__ sb,
                                            const float* __restrict__ sp,
                                            int i, int o,
                                            __hip_bfloat16* __restrict__ W) {
    float sbv = sb[i * O_DIM + o];
    float spv = sp[i * O_DIM + o];
    const float* cf = coef + (size_t)(i * O_DIM + o) * NSPL;
    __align__(16) __hip_bfloat16 row[KPI];
#pragma unroll
    for (int k = 0; k < NSPL; ++k) row[k] = __float2bfloat16(spv * cf[k]);
    __hip_bfloat16 whi = __float2bfloat16(sbv);
    __hip_bfloat16 wlo = __float2bfloat16(sbv - __bfloat162float(whi));
    row[8]  = whi;
    row[9]  = wlo;
    row[10] = whi;
    row[11] = __float2bfloat16(0.0f);
    uint2* dst = (uint2*)(W + (size_t)o * KDIM + i * KPI);
    const uint2* src = (const uint2*)row;
    dst[0] = src[0]; dst[1] = src[1]; dst[2] = src[2];
}

// ---------------------------------------------------------------------------
// prep: one launch for Wt-build (all 3 layers) + layer-0 features.
// Wt job (blocks 0..3071): per block a (64 i x 4 o) tile of one layer; lane
// map i = i0 + (t>>2), o = o0 + (t&3) -> 4 consecutive lanes read one FULL
// 128B line of coef (fixes R0-R3's ~4x over-fetch: old map had 16KB lane
// stride). Writes: per o-row, 64 lanes-worth of consecutive i -> contiguous.
// Feature job (blocks 3072..5119): identical to verified build_features_x.
// ---------------------------------------------------------------------------
#define WT_BLOCKS   3072   // 3 layers x (8 i-tiles x 128 o-tiles)
#define FEAT_BLOCKS 2048   // NBATCH*I_DIM / 256
__global__ __launch_bounds__(256)
void prep_kernel(const float* __restrict__ x0, const float* __restrict__ gr0,
                 const float* __restrict__ c0, const float* __restrict__ sb0, const float* __restrict__ sp0,
                 const float* __restrict__ c1, const float* __restrict__ sb1, const float* __restrict__ sp1,
                 const float* __restrict__ c2, const float* __restrict__ sb2, const float* __restrict__ sp2,
                 __hip_bfloat16* __restrict__ Wt,   // [3][O_DIM][KDIM]
                 __hip_bfloat16* __restrict__ F) {  // [NBATCH][KDIM]
    int b = blockIdx.x;
    int t = threadIdx.x;
    if (b < WT_BLOCKS) {
        int l   = b >> 10;            // 0..2
        int rem = b & 1023;
        int i0  = (rem & 7) * 64;     // 8 i-tiles
        int o0  = (rem >> 3) * 4;     // 128 o-tiles
        const float* coef = l == 0 ? c0  : (l == 1 ? c1  : c2);
        const float* sb   = l == 0 ? sb0 : (l == 1 ? sb1 : sb2);
        const float* sp   = l == 0 ? sp0 : (l == 1 ? sp1 : sp2);
        wt_row_core(coef, sb, sp, i0 + (t >> 2), o0 + (t & 3),
                    Wt + (size_t)l * O_DIM * KDIM);
    } else {
        int e = (b - WT_BLOCKS) * 256 + t;   // b*512+i over [0, NBATCH*I_DIM)
        features_core(x0[e], gr0, e & (I_DIM - 1), F + (size_t)e * KPI);
    }
}

// ---------------------------------------------------------------------------
// featsum: x = sum of SPLITK partials, then features. reduce: final splitK sum.
// ---------------------------------------------------------------------------
__global__ __launch_bounds__(256)
void build_features_sum(const float* __restrict__ P,  // [SPLITK][NBATCH*I_DIM]
                        const float* __restrict__ grid,
                        __hip_bfloat16* __restrict__ F) {
    int tid = blockIdx.x * blockDim.x + threadIdx.x;
    float xv = 0.f;
#pragma unroll
    for (int s = 0; s < SPLITK; ++s) xv += P[(size_t)s * NBATCH * I_DIM + tid];
    features_core(xv, grid, tid & (I_DIM - 1), F + (size_t)tid * KPI);
}

__global__ __launch_bounds__(256)
void reduce_out(const float* __restrict__ P, float* __restrict__ out) {
    int tid = blockIdx.x * blockDim.x + threadIdx.x;
    float v = 0.f;
#pragma unroll
    for (int s = 0; s < SPLITK; ++s) v += P[(size_t)s * NBATCH * O_DIM + tid];
    out[tid] = v;
}

// ---------------------------------------------------------------------------
// GEMM: P[ks][b,o] = sum_{k in seg ks} F[b,k] * Wt[o][k]   (bf16 MFMA, fp32 acc)
// R4: splitK=4, BM=BN=64, grid 16x8x4 = 512 blocks (2/CU, 8 waves/CU as R1).
// 4 waves in a 2x2 grid, wave tile 32x32 (acc[2][2]). global_load_lds w16;
// XOR-swizzled LDS rows (chunk j of row r at j^(r&7); 2-way aliasing free,
// m136). Halves P traffic vs splitK=8.
// ---------------------------------------------------------------------------
__global__ __launch_bounds__(256)
void gemm_kernel(const __hip_bfloat16* __restrict__ A,   // [NBATCH][KDIM]
                 const __hip_bfloat16* __restrict__ Wt,  // [O_DIM][KDIM]
                 float* __restrict__ P) {                // [SPLITK][NBATCH][O_DIM]
    __shared__ __hip_bfloat16 lA[BM * BK];   // 8 KB
    __shared__ __hip_bfloat16 lB[BN * BK];   // 8 KB

    int bm = blockIdx.x;        // 0..15
    int bn = blockIdx.y;        // 0..7
    int ks = blockIdx.z;        // 0..3
    int tid = threadIdx.x;
    int lane = tid & 63;
    int wave = tid >> 6;        // 0..3
    int wr = (wave & 1) * 32;
    int wc = (wave >> 1) * 32;
    int q  = lane >> 4;         // 0..3
    int ln = lane & 15;

    f32x4 acc[2][2];
#pragma unroll
    for (int a = 0; a < 2; ++a)
#pragma unroll
        for (int b = 0; b < 2; ++b) acc[a][b] = (f32x4){0.f, 0.f, 0.f, 0.f};

    const __hip_bfloat16* Abase = A  + (size_t)(bm * BM) * KDIM + ks * KSEG;
    const __hip_bfloat16* Bbase = Wt + (size_t)(bn * BN) * KDIM + ks * KSEG;

    for (int kt = 0; kt < KSEG; kt += BK) {
        __syncthreads();
        // A: 512 chunks of 16B (64 rows x 8); 4 waves x 2 calls x 64 lanes.
        // LDS dest wave-uniform base (HW adds lane*16); source chunk
        // j = (pos&7) ^ (row&7) (XOR swizzle).
#pragma unroll
        for (int c = 0; c < 2; ++c) {
            int cc = wave * 128 + c * 64 + lane;
            int r = cc >> 3, j = (cc & 7) ^ (r & 7);
            gload_lds16(Abase + (size_t)r * KDIM + kt + j * 8,
                        lA + (size_t)(wave * 128 + c * 64) * 8);
        }
#pragma unroll
        for (int c = 0; c < 2; ++c) {
            int cc = wave * 128 + c * 64 + lane;
            int r = cc >> 3, j = (cc & 7) ^ (r & 7);
            gload_lds16(Bbase + (size_t)r * KDIM + kt + j * 8,
                        lB + (size_t)(wave * 128 + c * 64) * 8);
        }
        __syncthreads();   // vmcnt(0) drain before s_barrier

#pragma unroll
        for (int kh = 0; kh < 2; ++kh) {
            bf16x8 af[2], bfr[2];
#pragma unroll
            for (int rt = 0; rt < 2; ++rt) {
                int row = wr + rt * 16 + ln;
                af[rt] = *(const bf16x8*)(lA + row * BK + (((kh * 4 + q) ^ (row & 7)) * 8));
            }
#pragma unroll
            for (int ct = 0; ct < 2; ++ct) {
                int row = wc + ct * 16 + ln;
                bfr[ct] = *(const bf16x8*)(lB + row * BK + (((kh * 4 + q) ^ (row & 7)) * 8));
            }
#pragma unroll
            for (int rt = 0; rt < 2; ++rt)
#pragma unroll
                for (int ct = 0; ct < 2; ++ct)
                    acc[rt][ct] = __builtin_amdgcn_mfma_f32_16x16x32_bf16(
                        af[rt], bfr[ct], acc[rt][ct], 0, 0, 0);
        }
    }

    // epilogue: C/D layout col = lane&15, row = quad*4 + reg (round-0 verified)
    float* Pp = P + (size_t)ks * NBATCH * O_DIM;
    int orow = bm * BM + wr;
    int ocol = bn * BN + wc + ln;
#pragma unroll
    for (int rt = 0; rt < 2; ++rt)
#pragma unroll
        for (int ct = 0; ct < 2; ++ct)
#pragma unroll
            for (int r = 0; r < 4; ++r)
                Pp[(size_t)(orow + rt * 16 + q * 4 + r) * O_DIM + ocol + ct * 16]
                    = acc[rt][ct][r];
}

// ---------------------------------------------------------------------------
extern "C" void kernel_launch(void* const* d_in, const int* in_sizes, int n_in,
                              void* d_out, int out_size, void* d_ws, size_t ws_size,
                              hipStream_t stream) {
    const float* x0  = (const float*)d_in[0];
    const float* gr0 = (const float*)d_in[1];
    const float* c0  = (const float*)d_in[2];
    const float* sb0 = (const float*)d_in[3];
    const float* sp0 = (const float*)d_in[4];
    const float* gr1 = (const float*)d_in[5];
    const float* c1  = (const float*)d_in[6];
    const float* sb1 = (const float*)d_in[7];
    const float* sp1 = (const float*)d_in[8];
    const float* gr2 = (const float*)d_in[9];
    const float* c2  = (const float*)d_in[10];
    const float* sb2 = (const float*)d_in[11];
    const float* sp2 = (const float*)d_in[12];

    char* ws = (char*)d_ws;
    const size_t wt_bytes = (size_t)O_DIM * KDIM * sizeof(__hip_bfloat16);   // 6.3 MB/layer
    const size_t f_bytes  = (size_t)NBATCH * KDIM * sizeof(__hip_bfloat16);  // 12.6 MB
    __hip_bfloat16* Wt = (__hip_bfloat16*)ws;                  // 3 layers contiguous
    __hip_bfloat16* F  = (__hip_bfloat16*)(ws + 3 * wt_bytes);
    float* P = (float*)(ws + 3 * wt_bytes + f_bytes);          // [4][1024][512] = 8.4 MB
    float* out = (float*)d_out;

    prep_kernel<<<WT_BLOCKS + FEAT_BLOCKS, 256, 0, stream>>>(
        x0, gr0, c0, sb0, sp0, c1, sb1, sp1, c2, sb2, sp2, Wt, F);

    gemm_kernel<<<dim3(NBATCH / BM, O_DIM / BN, SPLITK), 256, 0, stream>>>(F, Wt, P);

    build_features_sum<<<(NBATCH * I_DIM) / 256, 256, 0, stream>>>(P, gr1, F);
    gemm_kernel<<<dim3(NBATCH / BM, O_DIM / BN, SPLITK), 256, 0, stream>>>(
        F, Wt + (size_t)O_DIM * KDIM, P);

    build_features_sum<<<(NBATCH * I_DIM) / 256, 256, 0, stream>>>(P, gr2, F);
    gemm_kernel<<<dim3(NBATCH / BM, O_DIM / BN, SPLITK), 256, 0, stream>>>(
        F, Wt + (size_t)2 * O_DIM * KDIM, P);

    reduce_out<<<(NBATCH * O_DIM) / 256, 256, 0, stream>>>(P, out);
}